// Round 1
// baseline (11.944 us; speedup 1.0000x reference)
//
#include <hip/hip_runtime.h>
#include <hip/hip_bf16.h>

// Gather: out[b, s, :] = hidden_states[b, pos[b, s], :]
// B=32, SEQ=4096, SENT=128, DIM=512, fp32.
// One thread per float4 of output: 32*128*(512/4) = 524288 threads
// = 2048 blocks x 256 threads exactly.

#define BATCH 32
#define SEQ   4096
#define SENT  128
#define DIM   512
#define DIM4  (DIM / 4)   // 128 float4 per row

__global__ __launch_bounds__(256) void gather_rows_kernel(
    const float4* __restrict__ hs,   // (B, SEQ, DIM/4)
    const int*    __restrict__ pos,  // (B, SENT)
    float4*       __restrict__ out)  // (B, SENT, DIM/4)
{
    const int tid = blockIdx.x * blockDim.x + threadIdx.x;  // [0, 524288)
    const int d   = tid & (DIM4 - 1);       // float4 lane within row
    const int row = tid >> 7;               // (b * SENT + s), DIM4 = 128 = 2^7
    const int b   = row >> 7;               // SENT = 128 = 2^7
    const int p   = pos[row];               // gathered sequence index

    out[tid] = hs[((size_t)b * SEQ + p) * DIM4 + d];
}

extern "C" void kernel_launch(void* const* d_in, const int* in_sizes, int n_in,
                              void* d_out, int out_size, void* d_ws, size_t ws_size,
                              hipStream_t stream) {
    const float4* hs  = (const float4*)d_in[0];
    const int*    pos = (const int*)d_in[1];
    float4*       out = (float4*)d_out;

    const int total4 = BATCH * SENT * DIM4;     // 524288
    gather_rows_kernel<<<total4 / 256, 256, 0, stream>>>(hs, pos, out);
}